// Round 1
// baseline (334.300 us; speedup 1.0000x reference)
//
#include <hip/hip_runtime.h>
#include <hip/hip_bf16.h>
#include <stdint.h>

#define B_N 8
#define T_N 1024
#define C_N 768
#define M_N (B_N*T_N)   // 8192

typedef __attribute__((ext_vector_type(4))) float f32x4;
typedef __attribute__((ext_vector_type(8))) short s16x8;
typedef __attribute__((ext_vector_type(4))) unsigned short u16x4;
typedef __attribute__((ext_vector_type(8))) unsigned short u16x8;

__device__ __forceinline__ unsigned short f2bf(float f){
  unsigned int u = __float_as_uint(f);
  u += 0x7FFFu + ((u >> 16) & 1u);   // round-to-nearest-even
  return (unsigned short)(u >> 16);
}

// ---------------------------------------------------------------------------
// Weight prep: bf16 conversion, perm folded into Wk/Wv rows and Wo columns.
// Also builds rev[] (inverse permutation).
// ---------------------------------------------------------------------------
__global__ __launch_bounds__(256) void prep_weights(
    const float* __restrict__ Wk, const float* __restrict__ Wv,
    const float* __restrict__ Wr, const float* __restrict__ Wo,
    const int* __restrict__ perm,
    unsigned short* __restrict__ Wkp, unsigned short* __restrict__ Wvp,
    unsigned short* __restrict__ Wrb, unsigned short* __restrict__ Wop,
    int* __restrict__ rev)
{
  int idx = blockIdx.x*256 + threadIdx.x;   // [0, C_N*C_N)
  int r = idx / C_N, c = idx - r*C_N;
  int pr = perm[r];
  Wkp[idx] = f2bf(Wk[pr*C_N + c]);
  Wvp[idx] = f2bf(Wv[pr*C_N + c]);
  Wrb[idx] = f2bf(Wr[idx]);
  Wop[idx] = f2bf(Wo[r*C_N + perm[c]]);
  if (idx < C_N) rev[perm[idx]] = idx;
}

// ---------------------------------------------------------------------------
// q_shift + token-mix fused; emits xk/xv/xr in bf16 for the MFMA GEMMs.
// groups of 192 channels: 0: src (h, w-1); 1: (h, w+1); 2: (h-1, w); 3: (h+1, w)
// ---------------------------------------------------------------------------
__global__ __launch_bounds__(256) void mix_kernel(
    const float* __restrict__ x,
    const float* __restrict__ mk, const float* __restrict__ mv, const float* __restrict__ mr,
    unsigned short* __restrict__ xk, unsigned short* __restrict__ xv, unsigned short* __restrict__ xr)
{
  int idx = blockIdx.x*256 + threadIdx.x;       // [0, M_N*C_N/4)
  int n  = idx / (C_N/4);
  int c4 = (idx - n*(C_N/4)) * 4;
  int t = n & (T_N-1);
  int h = t >> 5, w = t & 31;
  int grp = c4 / 192;
  int dh = (grp==2) ? -1 : (grp==3) ? 1 : 0;
  int dw = (grp==0) ? -1 : (grp==1) ? 1 : 0;
  int h2 = h + dh, w2 = w + dw;
  bool valid = ((unsigned)h2 < 32u) && ((unsigned)w2 < 32u);
  f32x4 xc = *(const f32x4*)(x + (size_t)n*C_N + c4);
  f32x4 xx = {0.f,0.f,0.f,0.f};
  if (valid) xx = *(const f32x4*)(x + (size_t)(n + dh*32 + dw)*C_N + c4);
  f32x4 vk = *(const f32x4*)(mk + c4);
  f32x4 vv = *(const f32x4*)(mv + c4);
  f32x4 vr = *(const f32x4*)(mr + c4);
  u16x4 ok, ov, orr;
  #pragma unroll
  for (int i=0;i<4;++i){
    float d = xc[i] - xx[i];
    ok[i]  = f2bf(xx[i] + vk[i]*d);
    ov[i]  = f2bf(xx[i] + vv[i]*d);
    orr[i] = f2bf(xx[i] + vr[i]*d);
  }
  *(u16x4*)(xk + (size_t)n*C_N + c4) = ok;
  *(u16x4*)(xv + (size_t)n*C_N + c4) = ov;
  *(u16x4*)(xr + (size_t)n*C_N + c4) = orr;
}

// ---------------------------------------------------------------------------
// 128x128x64 bf16 MFMA GEMM, C = A (MxK) * Bw^T (NxK rows).
// blockIdx.z: 0 -> kp, 1 -> vp, 2 -> sigmoid + rev-scatter into srp.
// ---------------------------------------------------------------------------
__global__ __launch_bounds__(256) void gemm_kvr(
    const unsigned short* __restrict__ xk, const unsigned short* __restrict__ xv,
    const unsigned short* __restrict__ xr,
    const unsigned short* __restrict__ Wkp, const unsigned short* __restrict__ Wvp,
    const unsigned short* __restrict__ Wrb,
    const int* __restrict__ rev,
    float* __restrict__ kp, float* __restrict__ vp, float* __restrict__ srp)
{
  const int z = blockIdx.z;
  const unsigned short* A  = (z==0)? xk  : (z==1)? xv  : xr;
  const unsigned short* Bw = (z==0)? Wkp : (z==1)? Wvp : Wrb;
  const int m0 = blockIdx.x*128, n0 = blockIdx.y*128;
  __shared__ __align__(16) unsigned short As[128][72];
  __shared__ __align__(16) unsigned short Bs[128][72];
  const int tid = threadIdx.x;
  const int lane = tid & 63, wid = tid >> 6;
  const int wr = wid >> 1, wc = wid & 1;
  f32x4 acc[4][4];
  #pragma unroll
  for (int i=0;i<4;++i)
    #pragma unroll
    for (int j=0;j<4;++j) acc[i][j] = (f32x4){0.f,0.f,0.f,0.f};
  const int arow = tid >> 3, acol8 = (tid & 7)*8;
  for (int k0 = 0; k0 < C_N; k0 += 64){
    #pragma unroll
    for (int it=0; it<4; ++it){
      int r = arow + it*32;
      *(u16x8*)&As[r][acol8] = *(const u16x8*)&A [(size_t)(m0+r)*C_N + k0 + acol8];
      *(u16x8*)&Bs[r][acol8] = *(const u16x8*)&Bw[(size_t)(n0+r)*C_N + k0 + acol8];
    }
    __syncthreads();
    const int lr = lane & 15;
    #pragma unroll
    for (int kk=0; kk<64; kk+=32){
      const int lk = kk + (lane>>4)*8;
      s16x8 af[4], bfr[4];
      #pragma unroll
      for (int mi=0;mi<4;++mi) af[mi]  = *(const s16x8*)&As[wr*64 + mi*16 + lr][lk];
      #pragma unroll
      for (int ni=0;ni<4;++ni) bfr[ni] = *(const s16x8*)&Bs[wc*64 + ni*16 + lr][lk];
      #pragma unroll
      for (int mi=0;mi<4;++mi)
        #pragma unroll
        for (int ni=0;ni<4;++ni)
          acc[mi][ni] = __builtin_amdgcn_mfma_f32_16x16x32_bf16(af[mi], bfr[ni], acc[mi][ni], 0,0,0);
    }
    __syncthreads();
  }
  const int lr4 = (lane>>4)*4, lc = lane & 15;
  #pragma unroll
  for (int mi=0;mi<4;++mi){
    #pragma unroll
    for (int ni=0;ni<4;++ni){
      #pragma unroll
      for (int i=0;i<4;++i){
        int m = m0 + wr*64 + mi*16 + lr4 + i;
        int n = n0 + wc*64 + ni*16 + lc;
        float val = acc[mi][ni][i];
        if (z==0)      kp[(size_t)m*C_N + n] = val;
        else if (z==1) vp[(size_t)m*C_N + n] = val;
        else           srp[(size_t)m*C_N + rev[n]] = 1.f/(1.f + __expf(-val));
      }
    }
  }
}

// ---------------------------------------------------------------------------
// Final GEMM: out = z' (M x C, bf16) * Wop^T ; plain f32 epilogue into d_out.
// ---------------------------------------------------------------------------
__global__ __launch_bounds__(256) void gemm_out(
    const unsigned short* __restrict__ A, const unsigned short* __restrict__ Bw,
    float* __restrict__ out)
{
  const int m0 = blockIdx.x*128, n0 = blockIdx.y*128;
  __shared__ __align__(16) unsigned short As[128][72];
  __shared__ __align__(16) unsigned short Bs[128][72];
  const int tid = threadIdx.x;
  const int lane = tid & 63, wid = tid >> 6;
  const int wr = wid >> 1, wc = wid & 1;
  f32x4 acc[4][4];
  #pragma unroll
  for (int i=0;i<4;++i)
    #pragma unroll
    for (int j=0;j<4;++j) acc[i][j] = (f32x4){0.f,0.f,0.f,0.f};
  const int arow = tid >> 3, acol8 = (tid & 7)*8;
  for (int k0 = 0; k0 < C_N; k0 += 64){
    #pragma unroll
    for (int it=0; it<4; ++it){
      int r = arow + it*32;
      *(u16x8*)&As[r][acol8] = *(const u16x8*)&A [(size_t)(m0+r)*C_N + k0 + acol8];
      *(u16x8*)&Bs[r][acol8] = *(const u16x8*)&Bw[(size_t)(n0+r)*C_N + k0 + acol8];
    }
    __syncthreads();
    const int lr = lane & 15;
    #pragma unroll
    for (int kk=0; kk<64; kk+=32){
      const int lk = kk + (lane>>4)*8;
      s16x8 af[4], bfr[4];
      #pragma unroll
      for (int mi=0;mi<4;++mi) af[mi]  = *(const s16x8*)&As[wr*64 + mi*16 + lr][lk];
      #pragma unroll
      for (int ni=0;ni<4;++ni) bfr[ni] = *(const s16x8*)&Bs[wc*64 + ni*16 + lr][lk];
      #pragma unroll
      for (int mi=0;mi<4;++mi)
        #pragma unroll
        for (int ni=0;ni<4;++ni)
          acc[mi][ni] = __builtin_amdgcn_mfma_f32_16x16x32_bf16(af[mi], bfr[ni], acc[mi][ni], 0,0,0);
    }
    __syncthreads();
  }
  const int lr4 = (lane>>4)*4, lc = lane & 15;
  #pragma unroll
  for (int mi=0;mi<4;++mi)
    #pragma unroll
    for (int ni=0;ni<4;++ni)
      #pragma unroll
      for (int i=0;i<4;++i){
        int m = m0 + wr*64 + mi*16 + lr4 + i;
        int n = n0 + wc*64 + ni*16 + lc;
        out[(size_t)m*C_N + n] = acc[mi][ni][i];
      }
}

// ---------------------------------------------------------------------------
// WKV sequential scan. One lane per (b, permuted-channel j). Reads kp/vp/srp
// (all already in j-order), writes z'[n][j] = bf16(srp * y) for the out-GEMM.
// ---------------------------------------------------------------------------
__global__ __launch_bounds__(64) void wkv_kernel(
    const float* __restrict__ kp, const float* __restrict__ vp,
    const float* __restrict__ srp,
    const float* __restrict__ decay, const float* __restrict__ first,
    unsigned short* __restrict__ zp)
{
  int g = blockIdx.x*64 + threadIdx.x;   // [0, B_N*C_N)
  int b = g / C_N, j = g - b*C_N;
  float w = -__expf(decay[j] * (1.0f/T_N));
  float u = first[j] * (1.0f/T_N);
  float a = 0.f, bb = 0.f, p = -1e38f;
  size_t base = (size_t)b*T_N*C_N + j;
  for (int t = 0; t < T_N; ++t){
    size_t o = base + (size_t)t*C_N;
    float kt = kp[o], vt = vp[o];
    float uk = u + kt;
    float q  = fmaxf(p, uk);
    float e1 = __expf(p - q), e2 = __expf(uk - q);
    float y  = __fdividef(e1*a + e2*vt, e1*bb + e2);
    zp[o] = f2bf(srp[o] * y);
    float pw = p + w;
    float q2 = fmaxf(pw, kt);
    float e1b = __expf(pw - q2), e2b = __expf(kt - q2);
    a  = e1b*a + e2b*vt;
    bb = e1b*bb + e2b;
    p  = q2;
  }
}

// ---------------------------------------------------------------------------
extern "C" void kernel_launch(void* const* d_in, const int* in_sizes, int n_in,
                              void* d_out, int out_size, void* d_ws, size_t ws_size,
                              hipStream_t stream)
{
  const float* x     = (const float*)d_in[0];
  const float* Wk    = (const float*)d_in[1];
  const float* Wv    = (const float*)d_in[2];
  const float* Wr    = (const float*)d_in[3];
  const float* Wo    = (const float*)d_in[4];
  const float* decay = (const float*)d_in[5];
  const float* first = (const float*)d_in[6];
  const float* mk    = (const float*)d_in[7];
  const float* mv    = (const float*)d_in[8];
  const float* mr    = (const float*)d_in[9];
  const int*   perm  = (const int*)d_in[10];
  float* out = (float*)d_out;

  char* ws = (char*)d_ws;
  size_t off = 0;
  auto alloc = [&](size_t bytes)->char* {
    char* p = ws + off;
    off += (bytes + 255) & ~(size_t)255;
    return p;
  };
  const size_t MC = (size_t)M_N * C_N;      // 6291456
  const size_t CC = (size_t)C_N * C_N;      // 589824
  unsigned short* xk  = (unsigned short*)alloc(MC*2);
  unsigned short* xv  = (unsigned short*)alloc(MC*2);
  unsigned short* xr  = (unsigned short*)alloc(MC*2);
  unsigned short* zp  = (unsigned short*)alloc(MC*2);
  unsigned short* Wkp = (unsigned short*)alloc(CC*2);
  unsigned short* Wvp = (unsigned short*)alloc(CC*2);
  unsigned short* Wrb = (unsigned short*)alloc(CC*2);
  unsigned short* Wop = (unsigned short*)alloc(CC*2);
  int*   rev = (int*)alloc(C_N*4);
  float* kp  = (float*)alloc(MC*4);
  float* vp  = (float*)alloc(MC*4);
  float* srp = (float*)alloc(MC*4);

  prep_weights<<<dim3(CC/256), dim3(256), 0, stream>>>(Wk, Wv, Wr, Wo, perm,
                                                       Wkp, Wvp, Wrb, Wop, rev);
  mix_kernel<<<dim3(MC/4/256), dim3(256), 0, stream>>>(x, mk, mv, mr, xk, xv, xr);
  gemm_kvr<<<dim3(M_N/128, C_N/128, 3), dim3(256), 0, stream>>>(
      xk, xv, xr, Wkp, Wvp, Wrb, rev, kp, vp, srp);
  wkv_kernel<<<dim3(B_N*C_N/64), dim3(64), 0, stream>>>(kp, vp, srp, decay, first, zp);
  gemm_out<<<dim3(M_N/128, C_N/128), dim3(256), 0, stream>>>(zp, Wop, out);
}

// Round 3
// 148.608 us; speedup vs baseline: 2.2495x; 2.2495x over previous
//
#include <hip/hip_runtime.h>
#include <hip/hip_bf16.h>
#include <stdint.h>

#define B_N 8
#define T_N 1024
#define C_N 768
#define M_N (B_N*T_N)   // 8192
#define NCH 32          // chunks along T
#define LCH (T_N/NCH)   // 32

typedef __attribute__((ext_vector_type(4))) float f32x4;
typedef __attribute__((ext_vector_type(8))) short s16x8;
typedef __attribute__((ext_vector_type(4))) unsigned short u16x4;
typedef __attribute__((ext_vector_type(8))) unsigned short u16x8;

__device__ __forceinline__ unsigned short f2bf(float f){
  unsigned int u = __float_as_uint(f);
  u += 0x7FFFu + ((u >> 16) & 1u);   // round-to-nearest-even
  return (unsigned short)(u >> 16);
}

// ---------------------------------------------------------------------------
// Weight prep: bf16 conversion, perm folded into Wk/Wv rows and Wo columns.
// ---------------------------------------------------------------------------
__global__ __launch_bounds__(256) void prep_weights(
    const float* __restrict__ Wk, const float* __restrict__ Wv,
    const float* __restrict__ Wr, const float* __restrict__ Wo,
    const int* __restrict__ perm,
    unsigned short* __restrict__ Wkp, unsigned short* __restrict__ Wvp,
    unsigned short* __restrict__ Wrb, unsigned short* __restrict__ Wop,
    int* __restrict__ rev)
{
  int idx = blockIdx.x*256 + threadIdx.x;   // [0, C_N*C_N)
  int r = idx / C_N, c = idx - r*C_N;
  int pr = perm[r];
  Wkp[idx] = f2bf(Wk[pr*C_N + c]);
  Wvp[idx] = f2bf(Wv[pr*C_N + c]);
  Wrb[idx] = f2bf(Wr[idx]);
  Wop[idx] = f2bf(Wo[r*C_N + perm[c]]);
  if (idx < C_N) rev[perm[idx]] = idx;
}

// ---------------------------------------------------------------------------
// q_shift + token-mix fused; emits xk/xv/xr in bf16 for the MFMA GEMMs.
// ---------------------------------------------------------------------------
__global__ __launch_bounds__(256) void mix_kernel(
    const float* __restrict__ x,
    const float* __restrict__ mk, const float* __restrict__ mv, const float* __restrict__ mr,
    unsigned short* __restrict__ xk, unsigned short* __restrict__ xv, unsigned short* __restrict__ xr)
{
  int idx = blockIdx.x*256 + threadIdx.x;       // [0, M_N*C_N/4)
  int n  = idx / (C_N/4);
  int c4 = (idx - n*(C_N/4)) * 4;
  int t = n & (T_N-1);
  int h = t >> 5, w = t & 31;
  int grp = c4 / 192;
  int dh = (grp==2) ? -1 : (grp==3) ? 1 : 0;
  int dw = (grp==0) ? -1 : (grp==1) ? 1 : 0;
  int h2 = h + dh, w2 = w + dw;
  bool valid = ((unsigned)h2 < 32u) && ((unsigned)w2 < 32u);
  f32x4 xc = *(const f32x4*)(x + (size_t)n*C_N + c4);
  f32x4 xx = {0.f,0.f,0.f,0.f};
  if (valid) xx = *(const f32x4*)(x + (size_t)(n + dh*32 + dw)*C_N + c4);
  f32x4 vk = *(const f32x4*)(mk + c4);
  f32x4 vv = *(const f32x4*)(mv + c4);
  f32x4 vr = *(const f32x4*)(mr + c4);
  u16x4 ok, ov, orr;
  #pragma unroll
  for (int i=0;i<4;++i){
    float d = xc[i] - xx[i];
    ok[i]  = f2bf(xx[i] + vk[i]*d);
    ov[i]  = f2bf(xx[i] + vv[i]*d);
    orr[i] = f2bf(xx[i] + vr[i]*d);
  }
  *(u16x4*)(xk + (size_t)n*C_N + c4) = ok;
  *(u16x4*)(xv + (size_t)n*C_N + c4) = ov;
  *(u16x4*)(xr + (size_t)n*C_N + c4) = orr;
}

// ---------------------------------------------------------------------------
// 128x128x64 bf16 MFMA GEMM, C = A (MxK) * Bw^T (NxK rows).
// blockIdx.z: 0 -> kp, 1 -> vp, 2 -> sigmoid + rev-scatter into srp
// (so that srp[m][j] = sr[m][perm[j]], matching the wkv stream / Wop fold).
// ---------------------------------------------------------------------------
__global__ __launch_bounds__(256) void gemm_kvr(
    const unsigned short* __restrict__ xk, const unsigned short* __restrict__ xv,
    const unsigned short* __restrict__ xr,
    const unsigned short* __restrict__ Wkp, const unsigned short* __restrict__ Wvp,
    const unsigned short* __restrict__ Wrb,
    const int* __restrict__ rev,
    float* __restrict__ kp, float* __restrict__ vp, float* __restrict__ srp)
{
  const int z = blockIdx.z;
  const unsigned short* A  = (z==0)? xk  : (z==1)? xv  : xr;
  const unsigned short* Bw = (z==0)? Wkp : (z==1)? Wvp : Wrb;
  const int m0 = blockIdx.x*128, n0 = blockIdx.y*128;
  __shared__ __align__(16) unsigned short As[128][72];
  __shared__ __align__(16) unsigned short Bs[128][72];
  const int tid = threadIdx.x;
  const int lane = tid & 63, wid = tid >> 6;
  const int wr = wid >> 1, wc = wid & 1;
  f32x4 acc[4][4];
  #pragma unroll
  for (int i=0;i<4;++i)
    #pragma unroll
    for (int j=0;j<4;++j) acc[i][j] = (f32x4){0.f,0.f,0.f,0.f};
  const int arow = tid >> 3, acol8 = (tid & 7)*8;
  for (int k0 = 0; k0 < C_N; k0 += 64){
    #pragma unroll
    for (int it=0; it<4; ++it){
      int r = arow + it*32;
      *(u16x8*)&As[r][acol8] = *(const u16x8*)&A [(size_t)(m0+r)*C_N + k0 + acol8];
      *(u16x8*)&Bs[r][acol8] = *(const u16x8*)&Bw[(size_t)(n0+r)*C_N + k0 + acol8];
    }
    __syncthreads();
    const int lr = lane & 15;
    #pragma unroll
    for (int kk=0; kk<64; kk+=32){
      const int lk = kk + (lane>>4)*8;
      s16x8 af[4], bfr[4];
      #pragma unroll
      for (int mi=0;mi<4;++mi) af[mi]  = *(const s16x8*)&As[wr*64 + mi*16 + lr][lk];
      #pragma unroll
      for (int ni=0;ni<4;++ni) bfr[ni] = *(const s16x8*)&Bs[wc*64 + ni*16 + lr][lk];
      #pragma unroll
      for (int mi=0;mi<4;++mi)
        #pragma unroll
        for (int ni=0;ni<4;++ni)
          acc[mi][ni] = __builtin_amdgcn_mfma_f32_16x16x32_bf16(af[mi], bfr[ni], acc[mi][ni], 0,0,0);
    }
    __syncthreads();
  }
  const int lr4 = (lane>>4)*4, lc = lane & 15;
  #pragma unroll
  for (int mi=0;mi<4;++mi){
    #pragma unroll
    for (int ni=0;ni<4;++ni){
      #pragma unroll
      for (int i=0;i<4;++i){
        int m = m0 + wr*64 + mi*16 + lr4 + i;
        int n = n0 + wc*64 + ni*16 + lc;
        float val = acc[mi][ni][i];
        if (z==0)      kp[(size_t)m*C_N + n] = val;
        else if (z==1) vp[(size_t)m*C_N + n] = val;
        else           srp[(size_t)m*C_N + rev[n]] = 1.f/(1.f + __expf(-val));
      }
    }
  }
}

// ---------------------------------------------------------------------------
// Final GEMM: out = zp (M x C, bf16) * Wop^T.
// ---------------------------------------------------------------------------
__global__ __launch_bounds__(256) void gemm_out(
    const unsigned short* __restrict__ A, const unsigned short* __restrict__ Bw,
    float* __restrict__ out)
{
  const int m0 = blockIdx.x*128, n0 = blockIdx.y*128;
  __shared__ __align__(16) unsigned short As[128][72];
  __shared__ __align__(16) unsigned short Bs[128][72];
  const int tid = threadIdx.x;
  const int lane = tid & 63, wid = tid >> 6;
  const int wr = wid >> 1, wc = wid & 1;
  f32x4 acc[4][4];
  #pragma unroll
  for (int i=0;i<4;++i)
    #pragma unroll
    for (int j=0;j<4;++j) acc[i][j] = (f32x4){0.f,0.f,0.f,0.f};
  const int arow = tid >> 3, acol8 = (tid & 7)*8;
  for (int k0 = 0; k0 < C_N; k0 += 64){
    #pragma unroll
    for (int it=0; it<4; ++it){
      int r = arow + it*32;
      *(u16x8*)&As[r][acol8] = *(const u16x8*)&A [(size_t)(m0+r)*C_N + k0 + acol8];
      *(u16x8*)&Bs[r][acol8] = *(const u16x8*)&Bw[(size_t)(n0+r)*C_N + k0 + acol8];
    }
    __syncthreads();
    const int lr = lane & 15;
    #pragma unroll
    for (int kk=0; kk<64; kk+=32){
      const int lk = kk + (lane>>4)*8;
      s16x8 af[4], bfr[4];
      #pragma unroll
      for (int mi=0;mi<4;++mi) af[mi]  = *(const s16x8*)&As[wr*64 + mi*16 + lr][lk];
      #pragma unroll
      for (int ni=0;ni<4;++ni) bfr[ni] = *(const s16x8*)&Bs[wc*64 + ni*16 + lr][lk];
      #pragma unroll
      for (int mi=0;mi<4;++mi)
        #pragma unroll
        for (int ni=0;ni<4;++ni)
          acc[mi][ni] = __builtin_amdgcn_mfma_f32_16x16x32_bf16(af[mi], bfr[ni], acc[mi][ni], 0,0,0);
    }
    __syncthreads();
  }
  const int lr4 = (lane>>4)*4, lc = lane & 15;
  #pragma unroll
  for (int mi=0;mi<4;++mi)
    #pragma unroll
    for (int ni=0;ni<4;++ni)
      #pragma unroll
      for (int i=0;i<4;++i){
        int m = m0 + wr*64 + mi*16 + lr4 + i;
        int n = n0 + wc*64 + ni*16 + lc;
        out[(size_t)m*C_N + n] = acc[mi][ni][i];
      }
}

// ---------------------------------------------------------------------------
// WKV chunked scan. A_t = e^w A_{t-1} + e^{k_t} v_t is linear/associative:
// phase1 = per-chunk local scan (zero init), phase2 = serial combine of NCH
// chunk summaries per (b,j) writing each chunk's INCOMING state in place,
// phase3 = replay each chunk from its incoming state emitting y (and the
// sigmoid-gated bf16 z for the out-GEMM; srp is already in wkv-stream order).
// Per-chunk array layout: g = (c*B + b)*C + j  (j coalesced).
// ---------------------------------------------------------------------------
__global__ __launch_bounds__(256) void wkv_phase1(
    const float* __restrict__ kp, const float* __restrict__ vp,
    const float* __restrict__ decay,
    float* __restrict__ sa, float* __restrict__ sb, float* __restrict__ sp)
{
  int g = blockIdx.x*256 + threadIdx.x;   // [0, NCH*B_N*C_N)
  int j = g % C_N;
  int cb = g / C_N;
  int b = cb % B_N, c = cb / B_N;
  float w = -__expf(decay[j] * (1.0f/T_N));
  float a = 0.f, bb = 0.f, p = -1e38f;
  size_t base = ((size_t)b*T_N + c*LCH)*C_N + j;
  #pragma unroll 4
  for (int t = 0; t < LCH; ++t){
    size_t o = base + (size_t)t*C_N;
    float kt = kp[o], vt = vp[o];
    float pw = p + w;
    float q2 = fmaxf(pw, kt);
    float e1 = __expf(pw - q2), e2 = __expf(kt - q2);
    a  = e1*a + e2*vt;
    bb = e1*bb + e2;
    p  = q2;
  }
  sa[g] = a; sb[g] = bb; sp[g] = p;
}

// Serial combine across chunks; overwrites (sa,sb,sp) in place with the
// INCOMING state of each chunk.
__global__ __launch_bounds__(256) void wkv_phase2(
    const float* __restrict__ decay,
    float* __restrict__ sa, float* __restrict__ sb, float* __restrict__ sp)
{
  int g = blockIdx.x*256 + threadIdx.x;   // [0, B_N*C_N)
  int j = g % C_N, b = g / C_N;
  float w = -__expf(decay[j] * (1.0f/T_N));
  float wL = w * (float)LCH;
  float a = 0.f, bb = 0.f, p = -1e38f;
  for (int c = 0; c < NCH; ++c){
    size_t idx = ((size_t)c*B_N + b)*C_N + j;
    float la = sa[idx], lb = sb[idx], lp = sp[idx];
    sa[idx] = a; sb[idx] = bb; sp[idx] = p;   // incoming state for chunk c
    float p1 = p + wL;
    float pn = fmaxf(p1, lp);
    float e1 = __expf(p1 - pn), e2 = __expf(lp - pn);
    a  = e1*a + e2*la;
    bb = e1*bb + e2*lb;
    p  = pn;
  }
}

__global__ __launch_bounds__(256) void wkv_phase3(
    const float* __restrict__ kp, const float* __restrict__ vp,
    const float* __restrict__ srp,
    const float* __restrict__ decay, const float* __restrict__ first,
    const float* __restrict__ sa, const float* __restrict__ sb,
    const float* __restrict__ sp,
    unsigned short* __restrict__ zp)
{
  int g = blockIdx.x*256 + threadIdx.x;   // [0, NCH*B_N*C_N)
  int j = g % C_N;
  int cb = g / C_N;
  int b = cb % B_N, c = cb / B_N;
  float w = -__expf(decay[j] * (1.0f/T_N));
  float u = first[j] * (1.0f/T_N);
  float a = sa[g], bb = sb[g], p = sp[g];
  size_t base = ((size_t)b*T_N + c*LCH)*C_N + j;
  #pragma unroll 2
  for (int t = 0; t < LCH; ++t){
    size_t o = base + (size_t)t*C_N;
    float kt = kp[o], vt = vp[o];
    float uk = u + kt;
    float q  = fmaxf(p, uk);
    float e1 = __expf(p - q), e2 = __expf(uk - q);
    float y  = __fdividef(e1*a + e2*vt, e1*bb + e2);
    zp[o] = f2bf(srp[o] * y);
    float pw = p + w;
    float q2 = fmaxf(pw, kt);
    float e1b = __expf(pw - q2), e2b = __expf(kt - q2);
    a  = e1b*a + e2b*vt;
    bb = e1b*bb + e2b;
    p  = q2;
  }
}

// ---------------------------------------------------------------------------
extern "C" void kernel_launch(void* const* d_in, const int* in_sizes, int n_in,
                              void* d_out, int out_size, void* d_ws, size_t ws_size,
                              hipStream_t stream)
{
  const float* x     = (const float*)d_in[0];
  const float* Wk    = (const float*)d_in[1];
  const float* Wv    = (const float*)d_in[2];
  const float* Wr    = (const float*)d_in[3];
  const float* Wo    = (const float*)d_in[4];
  const float* decay = (const float*)d_in[5];
  const float* first = (const float*)d_in[6];
  const float* mk    = (const float*)d_in[7];
  const float* mv    = (const float*)d_in[8];
  const float* mr    = (const float*)d_in[9];
  const int*   perm  = (const int*)d_in[10];
  float* out = (float*)d_out;

  char* ws = (char*)d_ws;
  size_t off = 0;
  auto alloc = [&](size_t bytes)->char* {
    char* p = ws + off;
    off += (bytes + 255) & ~(size_t)255;
    return p;
  };
  const size_t MC = (size_t)M_N * C_N;      // 6291456
  const size_t CC = (size_t)C_N * C_N;      // 589824
  const size_t SC = (size_t)NCH * B_N * C_N; // 196608
  unsigned short* xk  = (unsigned short*)alloc(MC*2);
  unsigned short* xv  = (unsigned short*)alloc(MC*2);
  unsigned short* xr  = (unsigned short*)alloc(MC*2);
  unsigned short* zp  = (unsigned short*)alloc(MC*2);
  unsigned short* Wkp = (unsigned short*)alloc(CC*2);
  unsigned short* Wvp = (unsigned short*)alloc(CC*2);
  unsigned short* Wrb = (unsigned short*)alloc(CC*2);
  unsigned short* Wop = (unsigned short*)alloc(CC*2);
  int*   rev = (int*)alloc(C_N*4);
  float* kp  = (float*)alloc(MC*4);
  float* vp  = (float*)alloc(MC*4);
  float* srp = (float*)alloc(MC*4);
  float* sa  = (float*)alloc(SC*4);
  float* sb  = (float*)alloc(SC*4);
  float* sp  = (float*)alloc(SC*4);

  prep_weights<<<dim3(CC/256), dim3(256), 0, stream>>>(Wk, Wv, Wr, Wo, perm,
                                                       Wkp, Wvp, Wrb, Wop, rev);
  mix_kernel<<<dim3(MC/4/256), dim3(256), 0, stream>>>(x, mk, mv, mr, xk, xv, xr);
  gemm_kvr<<<dim3(M_N/128, C_N/128, 3), dim3(256), 0, stream>>>(
      xk, xv, xr, Wkp, Wvp, Wrb, rev, kp, vp, srp);
  wkv_phase1<<<dim3(SC/256), dim3(256), 0, stream>>>(kp, vp, decay, sa, sb, sp);
  wkv_phase2<<<dim3(B_N*C_N/256), dim3(256), 0, stream>>>(decay, sa, sb, sp);
  wkv_phase3<<<dim3(SC/256), dim3(256), 0, stream>>>(kp, vp, srp, decay, first,
                                                     sa, sb, sp, zp);
  gemm_out<<<dim3(M_N/128, C_N/128), dim3(256), 0, stream>>>(zp, Wop, out);
}

// Round 4
// 135.433 us; speedup vs baseline: 2.4684x; 1.0973x over previous
//
#include <hip/hip_runtime.h>
#include <hip/hip_bf16.h>
#include <stdint.h>

#define B_N 8
#define T_N 1024
#define C_N 768
#define M_N (B_N*T_N)   // 8192
#define NCH 32          // chunks along T
#define LCH (T_N/NCH)   // 32
#define BK  64

typedef __attribute__((ext_vector_type(4))) float f32x4;
typedef __attribute__((ext_vector_type(8))) short s16x8;
typedef __attribute__((ext_vector_type(4))) unsigned short u16x4;

__device__ __forceinline__ unsigned short f2bf(float f){
  unsigned int u = __float_as_uint(f);
  u += 0x7FFFu + ((u >> 16) & 1u);   // round-to-nearest-even
  return (unsigned short)(u >> 16);
}

// async 16B global -> LDS (wave-uniform LDS base + lane*16, per-lane global src)
__device__ __forceinline__ void async16(const unsigned short* g, unsigned short* l){
  __builtin_amdgcn_global_load_lds(
      (const __attribute__((address_space(1))) unsigned int*)g,
      (__attribute__((address_space(3))) unsigned int*)l, 16, 0, 0);
}

// ---------------------------------------------------------------------------
// Weight prep: bf16, perm folded into Wk/Wv/Wr ROWS and Wo COLUMNS.
// With Wrp[c,:] = Wr[perm[c],:], the r-GEMM directly emits
// srp[m][c] = sigmoid-input for sr[m][perm[c]] -> zero scatter anywhere.
// ---------------------------------------------------------------------------
__global__ __launch_bounds__(256) void prep_weights(
    const float* __restrict__ Wk, const float* __restrict__ Wv,
    const float* __restrict__ Wr, const float* __restrict__ Wo,
    const int* __restrict__ perm,
    unsigned short* __restrict__ Wkp, unsigned short* __restrict__ Wvp,
    unsigned short* __restrict__ Wrp, unsigned short* __restrict__ Wop)
{
  int idx = blockIdx.x*256 + threadIdx.x;   // [0, C_N*C_N)
  int r = idx / C_N, c = idx - r*C_N;
  int pr = perm[r];
  Wkp[idx] = f2bf(Wk[pr*C_N + c]);
  Wvp[idx] = f2bf(Wv[pr*C_N + c]);
  Wrp[idx] = f2bf(Wr[pr*C_N + c]);
  Wop[idx] = f2bf(Wo[r*C_N + perm[c]]);
}

// ---------------------------------------------------------------------------
// q_shift + token-mix fused; emits xk/xv/xr in bf16 for the MFMA GEMMs.
// ---------------------------------------------------------------------------
__global__ __launch_bounds__(256) void mix_kernel(
    const float* __restrict__ x,
    const float* __restrict__ mk, const float* __restrict__ mv, const float* __restrict__ mr,
    unsigned short* __restrict__ xk, unsigned short* __restrict__ xv, unsigned short* __restrict__ xr)
{
  int idx = blockIdx.x*256 + threadIdx.x;       // [0, M_N*C_N/4)
  int n  = idx / (C_N/4);
  int c4 = (idx - n*(C_N/4)) * 4;
  int t = n & (T_N-1);
  int h = t >> 5, w = t & 31;
  int grp = c4 / 192;
  int dh = (grp==2) ? -1 : (grp==3) ? 1 : 0;
  int dw = (grp==0) ? -1 : (grp==1) ? 1 : 0;
  int h2 = h + dh, w2 = w + dw;
  bool valid = ((unsigned)h2 < 32u) && ((unsigned)w2 < 32u);
  f32x4 xc = *(const f32x4*)(x + (size_t)n*C_N + c4);
  f32x4 xx = {0.f,0.f,0.f,0.f};
  if (valid) xx = *(const f32x4*)(x + (size_t)(n + dh*32 + dw)*C_N + c4);
  f32x4 vk = *(const f32x4*)(mk + c4);
  f32x4 vv = *(const f32x4*)(mv + c4);
  f32x4 vr = *(const f32x4*)(mr + c4);
  u16x4 ok, ov, orr;
  #pragma unroll
  for (int i=0;i<4;++i){
    float d = xc[i] - xx[i];
    ok[i]  = f2bf(xx[i] + vk[i]*d);
    ov[i]  = f2bf(xx[i] + vv[i]*d);
    orr[i] = f2bf(xx[i] + vr[i]*d);
  }
  *(u16x4*)(xk + (size_t)n*C_N + c4) = ok;
  *(u16x4*)(xv + (size_t)n*C_N + c4) = ov;
  *(u16x4*)(xr + (size_t)n*C_N + c4) = orr;
}

// ---------------------------------------------------------------------------
// 128x128 bf16 MFMA GEMM, global_load_lds staging (m97 structure), linear LDS.
// C = A (MxK) * Bw^T (NxK rows). z: 0 -> kp, 1 -> vp, 2 -> sigmoid -> srp.
// All epilogues fully coalesced (perm folded into weights).
// ---------------------------------------------------------------------------
__global__ __launch_bounds__(256) void gemm_kvr(
    const unsigned short* __restrict__ xk, const unsigned short* __restrict__ xv,
    const unsigned short* __restrict__ xr,
    const unsigned short* __restrict__ Wkp, const unsigned short* __restrict__ Wvp,
    const unsigned short* __restrict__ Wrp,
    float* __restrict__ kp, float* __restrict__ vp, float* __restrict__ srp)
{
  const int z = blockIdx.z;
  const unsigned short* A  = (z==0)? xk  : (z==1)? xv  : xr;
  const unsigned short* Bw = (z==0)? Wkp : (z==1)? Wvp : Wrp;
  const int m0 = blockIdx.x*128, n0 = blockIdx.y*128;
  __shared__ __align__(16) unsigned short As[128*BK];
  __shared__ __align__(16) unsigned short Bs[128*BK];
  const int tid = threadIdx.x;
  const int lane = tid & 63, wid = tid >> 6;
  const int wr = wid >> 1, wc = wid & 1;
  f32x4 acc[4][4];
  #pragma unroll
  for (int i=0;i<4;++i)
    #pragma unroll
    for (int j=0;j<4;++j) acc[i][j] = (f32x4){0.f,0.f,0.f,0.f};

  const int srow = tid >> 3;           // 0..31
  const int scol = (tid & 7) * 8;      // 0..56 (granule of 8 bf16 = 16B)
  const int lr = lane & 15;
  const int lks = (lane >> 4) * 8;

  for (int k0 = 0; k0 < C_N; k0 += BK){
    #pragma unroll
    for (int it=0; it<4; ++it){
      int r = it*32 + srow;
      // LDS dest: wave-uniform base; HW writes lane l at base + l*16
      unsigned short* la = &As[(it*32 + wid*8)*BK];
      unsigned short* lb = &Bs[(it*32 + wid*8)*BK];
      async16(&A [(size_t)(m0+r)*C_N + k0 + scol], la);
      async16(&Bw[(size_t)(n0+r)*C_N + k0 + scol], lb);
    }
    __syncthreads();
    #pragma unroll
    for (int kk=0; kk<BK; kk+=32){
      const int lk = kk + lks;
      s16x8 af[4], bfr[4];
      #pragma unroll
      for (int mi=0;mi<4;++mi) af[mi]  = *(const s16x8*)&As[(wr*64 + mi*16 + lr)*BK + lk];
      #pragma unroll
      for (int ni=0;ni<4;++ni) bfr[ni] = *(const s16x8*)&Bs[(wc*64 + ni*16 + lr)*BK + lk];
      #pragma unroll
      for (int mi=0;mi<4;++mi)
        #pragma unroll
        for (int ni=0;ni<4;++ni)
          acc[mi][ni] = __builtin_amdgcn_mfma_f32_16x16x32_bf16(af[mi], bfr[ni], acc[mi][ni], 0,0,0);
    }
    __syncthreads();
  }
  const int lr4 = (lane>>4)*4, lc = lane & 15;
  #pragma unroll
  for (int mi=0;mi<4;++mi){
    #pragma unroll
    for (int ni=0;ni<4;++ni){
      #pragma unroll
      for (int i=0;i<4;++i){
        int m = m0 + wr*64 + mi*16 + lr4 + i;
        int n = n0 + wc*64 + ni*16 + lc;
        float val = acc[mi][ni][i];
        if (z==0)      kp[(size_t)m*C_N + n] = val;
        else if (z==1) vp[(size_t)m*C_N + n] = val;
        else           srp[(size_t)m*C_N + n] = 1.f/(1.f + __expf(-val));
      }
    }
  }
}

// ---------------------------------------------------------------------------
// Final GEMM: out = zp (M x C, bf16) * Wop^T, same structure.
// ---------------------------------------------------------------------------
__global__ __launch_bounds__(256) void gemm_out(
    const unsigned short* __restrict__ A, const unsigned short* __restrict__ Bw,
    float* __restrict__ out)
{
  const int m0 = blockIdx.x*128, n0 = blockIdx.y*128;
  __shared__ __align__(16) unsigned short As[128*BK];
  __shared__ __align__(16) unsigned short Bs[128*BK];
  const int tid = threadIdx.x;
  const int lane = tid & 63, wid = tid >> 6;
  const int wr = wid >> 1, wc = wid & 1;
  f32x4 acc[4][4];
  #pragma unroll
  for (int i=0;i<4;++i)
    #pragma unroll
    for (int j=0;j<4;++j) acc[i][j] = (f32x4){0.f,0.f,0.f,0.f};

  const int srow = tid >> 3;
  const int scol = (tid & 7) * 8;
  const int lr = lane & 15;
  const int lks = (lane >> 4) * 8;

  for (int k0 = 0; k0 < C_N; k0 += BK){
    #pragma unroll
    for (int it=0; it<4; ++it){
      int r = it*32 + srow;
      unsigned short* la = &As[(it*32 + wid*8)*BK];
      unsigned short* lb = &Bs[(it*32 + wid*8)*BK];
      async16(&A [(size_t)(m0+r)*C_N + k0 + scol], la);
      async16(&Bw[(size_t)(n0+r)*C_N + k0 + scol], lb);
    }
    __syncthreads();
    #pragma unroll
    for (int kk=0; kk<BK; kk+=32){
      const int lk = kk + lks;
      s16x8 af[4], bfr[4];
      #pragma unroll
      for (int mi=0;mi<4;++mi) af[mi]  = *(const s16x8*)&As[(wr*64 + mi*16 + lr)*BK + lk];
      #pragma unroll
      for (int ni=0;ni<4;++ni) bfr[ni] = *(const s16x8*)&Bs[(wc*64 + ni*16 + lr)*BK + lk];
      #pragma unroll
      for (int mi=0;mi<4;++mi)
        #pragma unroll
        for (int ni=0;ni<4;++ni)
          acc[mi][ni] = __builtin_amdgcn_mfma_f32_16x16x32_bf16(af[mi], bfr[ni], acc[mi][ni], 0,0,0);
    }
    __syncthreads();
  }
  const int lr4 = (lane>>4)*4, lc = lane & 15;
  #pragma unroll
  for (int mi=0;mi<4;++mi)
    #pragma unroll
    for (int ni=0;ni<4;++ni)
      #pragma unroll
      for (int i=0;i<4;++i){
        int m = m0 + wr*64 + mi*16 + lr4 + i;
        int n = n0 + wc*64 + ni*16 + lc;
        out[(size_t)m*C_N + n] = acc[mi][ni][i];
      }
}

// ---------------------------------------------------------------------------
// WKV chunked scan (unchanged from round 3 — verified).
// ---------------------------------------------------------------------------
__global__ __launch_bounds__(256) void wkv_phase1(
    const float* __restrict__ kp, const float* __restrict__ vp,
    const float* __restrict__ decay,
    float* __restrict__ sa, float* __restrict__ sb, float* __restrict__ sp)
{
  int g = blockIdx.x*256 + threadIdx.x;   // [0, NCH*B_N*C_N)
  int j = g % C_N;
  int cb = g / C_N;
  int b = cb % B_N, c = cb / B_N;
  float w = -__expf(decay[j] * (1.0f/T_N));
  float a = 0.f, bb = 0.f, p = -1e38f;
  size_t base = ((size_t)b*T_N + c*LCH)*C_N + j;
  #pragma unroll 4
  for (int t = 0; t < LCH; ++t){
    size_t o = base + (size_t)t*C_N;
    float kt = kp[o], vt = vp[o];
    float pw = p + w;
    float q2 = fmaxf(pw, kt);
    float e1 = __expf(pw - q2), e2 = __expf(kt - q2);
    a  = e1*a + e2*vt;
    bb = e1*bb + e2;
    p  = q2;
  }
  sa[g] = a; sb[g] = bb; sp[g] = p;
}

__global__ __launch_bounds__(256) void wkv_phase2(
    const float* __restrict__ decay,
    float* __restrict__ sa, float* __restrict__ sb, float* __restrict__ sp)
{
  int g = blockIdx.x*256 + threadIdx.x;   // [0, B_N*C_N)
  int j = g % C_N, b = g / C_N;
  float w = -__expf(decay[j] * (1.0f/T_N));
  float wL = w * (float)LCH;
  float a = 0.f, bb = 0.f, p = -1e38f;
  for (int c = 0; c < NCH; ++c){
    size_t idx = ((size_t)c*B_N + b)*C_N + j;
    float la = sa[idx], lb = sb[idx], lp = sp[idx];
    sa[idx] = a; sb[idx] = bb; sp[idx] = p;   // incoming state for chunk c
    float p1 = p + wL;
    float pn = fmaxf(p1, lp);
    float e1 = __expf(p1 - pn), e2 = __expf(lp - pn);
    a  = e1*a + e2*la;
    bb = e1*bb + e2*lb;
    p  = pn;
  }
}

__global__ __launch_bounds__(256) void wkv_phase3(
    const float* __restrict__ kp, const float* __restrict__ vp,
    const float* __restrict__ srp,
    const float* __restrict__ decay, const float* __restrict__ first,
    const float* __restrict__ sa, const float* __restrict__ sb,
    const float* __restrict__ sp,
    unsigned short* __restrict__ zp)
{
  int g = blockIdx.x*256 + threadIdx.x;   // [0, NCH*B_N*C_N)
  int j = g % C_N;
  int cb = g / C_N;
  int b = cb % B_N, c = cb / B_N;
  float w = -__expf(decay[j] * (1.0f/T_N));
  float u = first[j] * (1.0f/T_N);
  float a = sa[g], bb = sb[g], p = sp[g];
  size_t base = ((size_t)b*T_N + c*LCH)*C_N + j;
  #pragma unroll 2
  for (int t = 0; t < LCH; ++t){
    size_t o = base + (size_t)t*C_N;
    float kt = kp[o], vt = vp[o];
    float uk = u + kt;
    float q  = fmaxf(p, uk);
    float e1 = __expf(p - q), e2 = __expf(uk - q);
    float y  = __fdividef(e1*a + e2*vt, e1*bb + e2);
    zp[o] = f2bf(srp[o] * y);
    float pw = p + w;
    float q2 = fmaxf(pw, kt);
    float e1b = __expf(pw - q2), e2b = __expf(kt - q2);
    a  = e1b*a + e2b*vt;
    bb = e1b*bb + e2b;
    p  = q2;
  }
}

// ---------------------------------------------------------------------------
extern "C" void kernel_launch(void* const* d_in, const int* in_sizes, int n_in,
                              void* d_out, int out_size, void* d_ws, size_t ws_size,
                              hipStream_t stream)
{
  const float* x     = (const float*)d_in[0];
  const float* Wk    = (const float*)d_in[1];
  const float* Wv    = (const float*)d_in[2];
  const float* Wr    = (const float*)d_in[3];
  const float* Wo    = (const float*)d_in[4];
  const float* decay = (const float*)d_in[5];
  const float* first = (const float*)d_in[6];
  const float* mk    = (const float*)d_in[7];
  const float* mv    = (const float*)d_in[8];
  const float* mr    = (const float*)d_in[9];
  const int*   perm  = (const int*)d_in[10];
  float* out = (float*)d_out;

  char* ws = (char*)d_ws;
  size_t off = 0;
  auto alloc = [&](size_t bytes)->char* {
    char* p = ws + off;
    off += (bytes + 255) & ~(size_t)255;
    return p;
  };
  const size_t MC = (size_t)M_N * C_N;       // 6291456
  const size_t CC = (size_t)C_N * C_N;       // 589824
  const size_t SC = (size_t)NCH * B_N * C_N; // 196608
  unsigned short* xk  = (unsigned short*)alloc(MC*2);
  unsigned short* xv  = (unsigned short*)alloc(MC*2);
  unsigned short* xr  = (unsigned short*)alloc(MC*2);
  unsigned short* zp  = (unsigned short*)alloc(MC*2);
  unsigned short* Wkp = (unsigned short*)alloc(CC*2);
  unsigned short* Wvp = (unsigned short*)alloc(CC*2);
  unsigned short* Wrp = (unsigned short*)alloc(CC*2);
  unsigned short* Wop = (unsigned short*)alloc(CC*2);
  float* kp  = (float*)alloc(MC*4);
  float* vp  = (float*)alloc(MC*4);
  float* srp = (float*)alloc(MC*4);
  float* sa  = (float*)alloc(SC*4);
  float* sb  = (float*)alloc(SC*4);
  float* sp  = (float*)alloc(SC*4);

  prep_weights<<<dim3(CC/256), dim3(256), 0, stream>>>(Wk, Wv, Wr, Wo, perm,
                                                       Wkp, Wvp, Wrp, Wop);
  mix_kernel<<<dim3(MC/4/256), dim3(256), 0, stream>>>(x, mk, mv, mr, xk, xv, xr);
  gemm_kvr<<<dim3(M_N/128, C_N/128, 3), dim3(256), 0, stream>>>(
      xk, xv, xr, Wkp, Wvp, Wrp, kp, vp, srp);
  wkv_phase1<<<dim3(SC/256), dim3(256), 0, stream>>>(kp, vp, decay, sa, sb, sp);
  wkv_phase2<<<dim3(B_N*C_N/256), dim3(256), 0, stream>>>(decay, sa, sb, sp);
  wkv_phase3<<<dim3(SC/256), dim3(256), 0, stream>>>(kp, vp, srp, decay, first,
                                                     sa, sb, sp, zp);
  gemm_out<<<dim3(M_N/128, C_N/128), dim3(256), 0, stream>>>(zp, Wop, out);
}

// Round 5
// 131.312 us; speedup vs baseline: 2.5458x; 1.0314x over previous
//
#include <hip/hip_runtime.h>
#include <hip/hip_bf16.h>
#include <stdint.h>

#define B_N 8
#define T_N 1024
#define C_N 768
#define M_N (B_N*T_N)   // 8192
#define NCH 32          // chunks along T
#define LCH (T_N/NCH)   // 32
#define BK  64

typedef __attribute__((ext_vector_type(4))) float f32x4;
typedef __attribute__((ext_vector_type(8))) short s16x8;
typedef __attribute__((ext_vector_type(4))) unsigned short u16x4;

__device__ __forceinline__ unsigned short f2bf(float f){
  unsigned int u = __float_as_uint(f);
  u += 0x7FFFu + ((u >> 16) & 1u);   // round-to-nearest-even
  return (unsigned short)(u >> 16);
}
__device__ __forceinline__ float bf2f(unsigned short h){
  return __uint_as_float(((unsigned int)h) << 16);
}

// async 16B global -> LDS (wave-uniform LDS base + lane*16, per-lane global src)
__device__ __forceinline__ void async16(const unsigned short* g, unsigned short* l){
  __builtin_amdgcn_global_load_lds(
      (const __attribute__((address_space(1))) unsigned int*)g,
      (__attribute__((address_space(3))) unsigned int*)l, 16, 0, 0);
}

// ---------------------------------------------------------------------------
// Weight prep: bf16; perm folded into Wk/Wv/Wr ROWS (one contiguous [2304][768]
// block) and into Wo COLUMNS.
// ---------------------------------------------------------------------------
__global__ __launch_bounds__(256) void prep_weights(
    const float* __restrict__ Wk, const float* __restrict__ Wv,
    const float* __restrict__ Wr, const float* __restrict__ Wo,
    const int* __restrict__ perm,
    unsigned short* __restrict__ Wall,   // [3*C_N][C_N]: k, v, r
    unsigned short* __restrict__ Wop)
{
  int idx = blockIdx.x*256 + threadIdx.x;   // [0, C_N*C_N)
  int r = idx / C_N, c = idx - r*C_N;
  int pr = perm[r];
  Wall[idx]            = f2bf(Wk[pr*C_N + c]);
  Wall[idx +   (size_t)C_N*C_N] = f2bf(Wv[pr*C_N + c]);
  Wall[idx + 2*(size_t)C_N*C_N] = f2bf(Wr[pr*C_N + c]);
  Wop[idx] = f2bf(Wo[r*C_N + perm[c]]);
}

// ---------------------------------------------------------------------------
// q_shift + token-mix fused; emits xk/xv/xr in bf16 for the MFMA GEMMs.
// ---------------------------------------------------------------------------
__global__ __launch_bounds__(256) void mix_kernel(
    const float* __restrict__ x,
    const float* __restrict__ mk, const float* __restrict__ mv, const float* __restrict__ mr,
    unsigned short* __restrict__ xk, unsigned short* __restrict__ xv, unsigned short* __restrict__ xr)
{
  int idx = blockIdx.x*256 + threadIdx.x;       // [0, M_N*C_N/4)
  int n  = idx / (C_N/4);
  int c4 = (idx - n*(C_N/4)) * 4;
  int t = n & (T_N-1);
  int h = t >> 5, w = t & 31;
  int grp = c4 / 192;
  int dh = (grp==2) ? -1 : (grp==3) ? 1 : 0;
  int dw = (grp==0) ? -1 : (grp==1) ? 1 : 0;
  int h2 = h + dh, w2 = w + dw;
  bool valid = ((unsigned)h2 < 32u) && ((unsigned)w2 < 32u);
  f32x4 xc = *(const f32x4*)(x + (size_t)n*C_N + c4);
  f32x4 xx = {0.f,0.f,0.f,0.f};
  if (valid) xx = *(const f32x4*)(x + (size_t)(n + dh*32 + dw)*C_N + c4);
  f32x4 vk = *(const f32x4*)(mk + c4);
  f32x4 vv = *(const f32x4*)(mv + c4);
  f32x4 vr = *(const f32x4*)(mr + c4);
  u16x4 ok, ov, orr;
  #pragma unroll
  for (int i=0;i<4;++i){
    float d = xc[i] - xx[i];
    ok[i]  = f2bf(xx[i] + vk[i]*d);
    ov[i]  = f2bf(xx[i] + vv[i]*d);
    orr[i] = f2bf(xx[i] + vr[i]*d);
  }
  *(u16x4*)(xk + (size_t)n*C_N + c4) = ok;
  *(u16x4*)(xv + (size_t)n*C_N + c4) = ov;
  *(u16x4*)(xr + (size_t)n*C_N + c4) = orr;
}

// ---------------------------------------------------------------------------
// Fused k/v/r GEMM: C[M x 2304] = A_z (M x 768) * Wall^T, 128x128 tiles.
// LDS XOR-swizzle (T2, both-sides): logical granule g of row r stored at
// physical granule g^(r&7); staging pre-swizzles the GLOBAL source (LDS dest
// stays linear for global_load_lds), ds_read applies the same XOR.
// Epilogue: n<768 -> kp (f32); <1536 -> vp (f32); else sigmoid -> srb (bf16).
// ---------------------------------------------------------------------------
__global__ __launch_bounds__(256) void gemm_kvr(
    const unsigned short* __restrict__ xk, const unsigned short* __restrict__ xv,
    const unsigned short* __restrict__ xr,
    const unsigned short* __restrict__ Wall,
    float* __restrict__ kp, float* __restrict__ vp, unsigned short* __restrict__ srb)
{
  const int m0 = blockIdx.x*128, n0 = blockIdx.y*128;
  const int z  = blockIdx.y / 6;                 // 6 n-blocks per 768 columns
  const unsigned short* A = (z==0)? xk : (z==1)? xv : xr;
  __shared__ __align__(16) unsigned short As[128*BK];
  __shared__ __align__(16) unsigned short Bs[128*BK];
  const int tid = threadIdx.x;
  const int lane = tid & 63, wid = tid >> 6;
  const int wr = wid >> 1, wc = wid & 1;
  f32x4 acc[4][4];
  #pragma unroll
  for (int i=0;i<4;++i)
    #pragma unroll
    for (int j=0;j<4;++j) acc[i][j] = (f32x4){0.f,0.f,0.f,0.f};

  const int srow = tid >> 3;                         // 0..31
  const int scol = (((tid & 7) ^ ((tid >> 3) & 7)) * 8);  // pre-swizzled source granule
  const int lr  = lane & 15;
  const int x7  = lr & 7;                            // read-side XOR term
  const int kh  = lane >> 4;                         // 0..3

  for (int k0 = 0; k0 < C_N; k0 += BK){
    #pragma unroll
    for (int it=0; it<4; ++it){
      int r = it*32 + srow;
      unsigned short* la = &As[(it*32 + wid*8)*BK];
      unsigned short* lb = &Bs[(it*32 + wid*8)*BK];
      async16(&A   [(size_t)(m0+r)*C_N + k0 + scol], la);
      async16(&Wall[(size_t)(n0+r)*C_N + k0 + scol], lb);
    }
    __syncthreads();
    #pragma unroll
    for (int kk=0; kk<BK; kk+=32){
      const int g = (kk>>3) + kh;                    // logical granule
      const int pg = (g ^ x7) << 3;                  // physical elem offset
      s16x8 af[4], bfr[4];
      #pragma unroll
      for (int mi=0;mi<4;++mi) af[mi]  = *(const s16x8*)&As[(wr*64 + mi*16 + lr)*BK + pg];
      #pragma unroll
      for (int ni=0;ni<4;++ni) bfr[ni] = *(const s16x8*)&Bs[(wc*64 + ni*16 + lr)*BK + pg];
      #pragma unroll
      for (int mi=0;mi<4;++mi)
        #pragma unroll
        for (int ni=0;ni<4;++ni)
          acc[mi][ni] = __builtin_amdgcn_mfma_f32_16x16x32_bf16(af[mi], bfr[ni], acc[mi][ni], 0,0,0);
    }
    __syncthreads();
  }
  const int lr4 = (lane>>4)*4, lc = lane & 15;
  const int colbase = n0 - z*C_N;
  #pragma unroll
  for (int mi=0;mi<4;++mi){
    #pragma unroll
    for (int ni=0;ni<4;++ni){
      #pragma unroll
      for (int i=0;i<4;++i){
        int m = m0 + wr*64 + mi*16 + lr4 + i;
        int n = colbase + wc*64 + ni*16 + lc;
        float val = acc[mi][ni][i];
        if (z==0)      kp[(size_t)m*C_N + n] = val;
        else if (z==1) vp[(size_t)m*C_N + n] = val;
        else           srb[(size_t)m*C_N + n] = f2bf(1.f/(1.f + __expf(-val)));
      }
    }
  }
}

// ---------------------------------------------------------------------------
// Final GEMM: out = zp (M x C, bf16) * Wop^T — same swizzled structure.
// ---------------------------------------------------------------------------
__global__ __launch_bounds__(256) void gemm_out(
    const unsigned short* __restrict__ A, const unsigned short* __restrict__ Bw,
    float* __restrict__ out)
{
  const int m0 = blockIdx.x*128, n0 = blockIdx.y*128;
  __shared__ __align__(16) unsigned short As[128*BK];
  __shared__ __align__(16) unsigned short Bs[128*BK];
  const int tid = threadIdx.x;
  const int lane = tid & 63, wid = tid >> 6;
  const int wr = wid >> 1, wc = wid & 1;
  f32x4 acc[4][4];
  #pragma unroll
  for (int i=0;i<4;++i)
    #pragma unroll
    for (int j=0;j<4;++j) acc[i][j] = (f32x4){0.f,0.f,0.f,0.f};

  const int srow = tid >> 3;
  const int scol = (((tid & 7) ^ ((tid >> 3) & 7)) * 8);
  const int lr  = lane & 15;
  const int x7  = lr & 7;
  const int kh  = lane >> 4;

  for (int k0 = 0; k0 < C_N; k0 += BK){
    #pragma unroll
    for (int it=0; it<4; ++it){
      int r = it*32 + srow;
      unsigned short* la = &As[(it*32 + wid*8)*BK];
      unsigned short* lb = &Bs[(it*32 + wid*8)*BK];
      async16(&A [(size_t)(m0+r)*C_N + k0 + scol], la);
      async16(&Bw[(size_t)(n0+r)*C_N + k0 + scol], lb);
    }
    __syncthreads();
    #pragma unroll
    for (int kk=0; kk<BK; kk+=32){
      const int g = (kk>>3) + kh;
      const int pg = (g ^ x7) << 3;
      s16x8 af[4], bfr[4];
      #pragma unroll
      for (int mi=0;mi<4;++mi) af[mi]  = *(const s16x8*)&As[(wr*64 + mi*16 + lr)*BK + pg];
      #pragma unroll
      for (int ni=0;ni<4;++ni) bfr[ni] = *(const s16x8*)&Bs[(wc*64 + ni*16 + lr)*BK + pg];
      #pragma unroll
      for (int mi=0;mi<4;++mi)
        #pragma unroll
        for (int ni=0;ni<4;++ni)
          acc[mi][ni] = __builtin_amdgcn_mfma_f32_16x16x32_bf16(af[mi], bfr[ni], acc[mi][ni], 0,0,0);
    }
    __syncthreads();
  }
  const int lr4 = (lane>>4)*4, lc = lane & 15;
  #pragma unroll
  for (int mi=0;mi<4;++mi)
    #pragma unroll
    for (int ni=0;ni<4;++ni)
      #pragma unroll
      for (int i=0;i<4;++i){
        int m = m0 + wr*64 + mi*16 + lr4 + i;
        int n = n0 + wc*64 + ni*16 + lc;
        out[(size_t)m*C_N + n] = acc[mi][ni][i];
      }
}

// ---------------------------------------------------------------------------
// WKV chunked scan (verified round 3). srb is bf16 now.
// ---------------------------------------------------------------------------
__global__ __launch_bounds__(256) void wkv_phase1(
    const float* __restrict__ kp, const float* __restrict__ vp,
    const float* __restrict__ decay,
    float* __restrict__ sa, float* __restrict__ sb, float* __restrict__ sp)
{
  int g = blockIdx.x*256 + threadIdx.x;   // [0, NCH*B_N*C_N)
  int j = g % C_N;
  int cb = g / C_N;
  int b = cb % B_N, c = cb / B_N;
  float w = -__expf(decay[j] * (1.0f/T_N));
  float a = 0.f, bb = 0.f, p = -1e38f;
  size_t base = ((size_t)b*T_N + c*LCH)*C_N + j;
  #pragma unroll 4
  for (int t = 0; t < LCH; ++t){
    size_t o = base + (size_t)t*C_N;
    float kt = kp[o], vt = vp[o];
    float pw = p + w;
    float q2 = fmaxf(pw, kt);
    float e1 = __expf(pw - q2), e2 = __expf(kt - q2);
    a  = e1*a + e2*vt;
    bb = e1*bb + e2;
    p  = q2;
  }
  sa[g] = a; sb[g] = bb; sp[g] = p;
}

__global__ __launch_bounds__(256) void wkv_phase2(
    const float* __restrict__ decay,
    float* __restrict__ sa, float* __restrict__ sb, float* __restrict__ sp)
{
  int g = blockIdx.x*256 + threadIdx.x;   // [0, B_N*C_N)
  int j = g % C_N, b = g / C_N;
  float w = -__expf(decay[j] * (1.0f/T_N));
  float wL = w * (float)LCH;
  float a = 0.f, bb = 0.f, p = -1e38f;
  for (int c = 0; c < NCH; ++c){
    size_t idx = ((size_t)c*B_N + b)*C_N + j;
    float la = sa[idx], lb = sb[idx], lp = sp[idx];
    sa[idx] = a; sb[idx] = bb; sp[idx] = p;   // incoming state for chunk c
    float p1 = p + wL;
    float pn = fmaxf(p1, lp);
    float e1 = __expf(p1 - pn), e2 = __expf(lp - pn);
    a  = e1*a + e2*la;
    bb = e1*bb + e2*lb;
    p  = pn;
  }
}

__global__ __launch_bounds__(256) void wkv_phase3(
    const float* __restrict__ kp, const float* __restrict__ vp,
    const unsigned short* __restrict__ srb,
    const float* __restrict__ decay, const float* __restrict__ first,
    const float* __restrict__ sa, const float* __restrict__ sb,
    const float* __restrict__ sp,
    unsigned short* __restrict__ zp)
{
  int g = blockIdx.x*256 + threadIdx.x;   // [0, NCH*B_N*C_N)
  int j = g % C_N;
  int cb = g / C_N;
  int b = cb % B_N, c = cb / B_N;
  float w = -__expf(decay[j] * (1.0f/T_N));
  float u = first[j] * (1.0f/T_N);
  float a = sa[g], bb = sb[g], p = sp[g];
  size_t base = ((size_t)b*T_N + c*LCH)*C_N + j;
  #pragma unroll 2
  for (int t = 0; t < LCH; ++t){
    size_t o = base + (size_t)t*C_N;
    float kt = kp[o], vt = vp[o];
    float uk = u + kt;
    float q  = fmaxf(p, uk);
    float e1 = __expf(p - q), e2 = __expf(uk - q);
    float y  = __fdividef(e1*a + e2*vt, e1*bb + e2);
    zp[o] = f2bf(bf2f(srb[o]) * y);
    float pw = p + w;
    float q2 = fmaxf(pw, kt);
    float e1b = __expf(pw - q2), e2b = __expf(kt - q2);
    a  = e1b*a + e2b*vt;
    bb = e1b*bb + e2b;
    p  = q2;
  }
}

// ---------------------------------------------------------------------------
extern "C" void kernel_launch(void* const* d_in, const int* in_sizes, int n_in,
                              void* d_out, int out_size, void* d_ws, size_t ws_size,
                              hipStream_t stream)
{
  const float* x     = (const float*)d_in[0];
  const float* Wk    = (const float*)d_in[1];
  const float* Wv    = (const float*)d_in[2];
  const float* Wr    = (const float*)d_in[3];
  const float* Wo    = (const float*)d_in[4];
  const float* decay = (const float*)d_in[5];
  const float* first = (const float*)d_in[6];
  const float* mk    = (const float*)d_in[7];
  const float* mv    = (const float*)d_in[8];
  const float* mr    = (const float*)d_in[9];
  const int*   perm  = (const int*)d_in[10];
  float* out = (float*)d_out;

  char* ws = (char*)d_ws;
  size_t off = 0;
  auto alloc = [&](size_t bytes)->char* {
    char* p = ws + off;
    off += (bytes + 255) & ~(size_t)255;
    return p;
  };
  const size_t MC = (size_t)M_N * C_N;       // 6291456
  const size_t CC = (size_t)C_N * C_N;       // 589824
  const size_t SC = (size_t)NCH * B_N * C_N; // 196608
  unsigned short* xk   = (unsigned short*)alloc(MC*2);
  unsigned short* xv   = (unsigned short*)alloc(MC*2);
  unsigned short* xr   = (unsigned short*)alloc(MC*2);
  unsigned short* zp   = (unsigned short*)alloc(MC*2);
  unsigned short* Wall = (unsigned short*)alloc(CC*3*2);  // k,v,r contiguous
  unsigned short* Wop  = (unsigned short*)alloc(CC*2);
  unsigned short* srb  = (unsigned short*)alloc(MC*2);
  float* kp  = (float*)alloc(MC*4);
  float* vp  = (float*)alloc(MC*4);
  float* sa  = (float*)alloc(SC*4);
  float* sb  = (float*)alloc(SC*4);
  float* sp  = (float*)alloc(SC*4);

  prep_weights<<<dim3(CC/256), dim3(256), 0, stream>>>(Wk, Wv, Wr, Wo, perm,
                                                       Wall, Wop);
  mix_kernel<<<dim3(MC/4/256), dim3(256), 0, stream>>>(x, mk, mv, mr, xk, xv, xr);
  gemm_kvr<<<dim3(M_N/128, 3*C_N/128), dim3(256), 0, stream>>>(
      xk, xv, xr, Wall, kp, vp, srb);
  wkv_phase1<<<dim3(SC/256), dim3(256), 0, stream>>>(kp, vp, decay, sa, sb, sp);
  wkv_phase2<<<dim3(B_N*C_N/256), dim3(256), 0, stream>>>(decay, sa, sb, sp);
  wkv_phase3<<<dim3(SC/256), dim3(256), 0, stream>>>(kp, vp, srb, decay, first,
                                                     sa, sb, sp, zp);
  gemm_out<<<dim3(M_N/128, C_N/128), dim3(256), 0, stream>>>(zp, Wop, out);
}

// Round 6
// 125.639 us; speedup vs baseline: 2.6608x; 1.0452x over previous
//
#include <hip/hip_runtime.h>
#include <hip/hip_bf16.h>
#include <stdint.h>

#define B_N 8
#define T_N 1024
#define C_N 768
#define M_N (B_N*T_N)   // 8192
#define NCH 32          // chunks along T
#define LCH (T_N/NCH)   // 32
#define BK  64

typedef __attribute__((ext_vector_type(4))) float f32x4;
typedef __attribute__((ext_vector_type(8))) short s16x8;
typedef __attribute__((ext_vector_type(4))) unsigned short u16x4;

__device__ __forceinline__ unsigned short f2bf(float f){
  unsigned int u = __float_as_uint(f);
  u += 0x7FFFu + ((u >> 16) & 1u);   // round-to-nearest-even
  return (unsigned short)(u >> 16);
}
__device__ __forceinline__ float bf2f(unsigned short h){
  return __uint_as_float(((unsigned int)h) << 16);
}

// async 16B global -> LDS (wave-uniform LDS base + lane*16, per-lane global src)
__device__ __forceinline__ void async16(const unsigned short* g, unsigned short* l){
  __builtin_amdgcn_global_load_lds(
      (const __attribute__((address_space(1))) unsigned int*)g,
      (__attribute__((address_space(3))) unsigned int*)l, 16, 0, 0);
}

// ---------------------------------------------------------------------------
// Weight prep: bf16; perm folded into Wk/Wv/Wr ROWS (one contiguous [2304][768]
// block) and into Wo COLUMNS.
// ---------------------------------------------------------------------------
__global__ __launch_bounds__(256) void prep_weights(
    const float* __restrict__ Wk, const float* __restrict__ Wv,
    const float* __restrict__ Wr, const float* __restrict__ Wo,
    const int* __restrict__ perm,
    unsigned short* __restrict__ Wall,   // [3*C_N][C_N]: k, v, r
    unsigned short* __restrict__ Wop)
{
  int idx = blockIdx.x*256 + threadIdx.x;   // [0, C_N*C_N)
  int r = idx / C_N, c = idx - r*C_N;
  int pr = perm[r];
  Wall[idx]            = f2bf(Wk[pr*C_N + c]);
  Wall[idx +   (size_t)C_N*C_N] = f2bf(Wv[pr*C_N + c]);
  Wall[idx + 2*(size_t)C_N*C_N] = f2bf(Wr[pr*C_N + c]);
  Wop[idx] = f2bf(Wo[r*C_N + perm[c]]);
}

// ---------------------------------------------------------------------------
// q_shift + token-mix fused; emits xk/xv/xr in bf16 for the MFMA GEMMs.
// ---------------------------------------------------------------------------
__global__ __launch_bounds__(256) void mix_kernel(
    const float* __restrict__ x,
    const float* __restrict__ mk, const float* __restrict__ mv, const float* __restrict__ mr,
    unsigned short* __restrict__ xk, unsigned short* __restrict__ xv, unsigned short* __restrict__ xr)
{
  int idx = blockIdx.x*256 + threadIdx.x;       // [0, M_N*C_N/4)
  int n  = idx / (C_N/4);
  int c4 = (idx - n*(C_N/4)) * 4;
  int t = n & (T_N-1);
  int h = t >> 5, w = t & 31;
  int grp = c4 / 192;
  int dh = (grp==2) ? -1 : (grp==3) ? 1 : 0;
  int dw = (grp==0) ? -1 : (grp==1) ? 1 : 0;
  int h2 = h + dh, w2 = w + dw;
  bool valid = ((unsigned)h2 < 32u) && ((unsigned)w2 < 32u);
  f32x4 xc = *(const f32x4*)(x + (size_t)n*C_N + c4);
  f32x4 xx = {0.f,0.f,0.f,0.f};
  if (valid) xx = *(const f32x4*)(x + (size_t)(n + dh*32 + dw)*C_N + c4);
  f32x4 vk = *(const f32x4*)(mk + c4);
  f32x4 vv = *(const f32x4*)(mv + c4);
  f32x4 vr = *(const f32x4*)(mr + c4);
  u16x4 ok, ov, orr;
  #pragma unroll
  for (int i=0;i<4;++i){
    float d = xc[i] - xx[i];
    ok[i]  = f2bf(xx[i] + vk[i]*d);
    ov[i]  = f2bf(xx[i] + vv[i]*d);
    orr[i] = f2bf(xx[i] + vr[i]*d);
  }
  *(u16x4*)(xk + (size_t)n*C_N + c4) = ok;
  *(u16x4*)(xv + (size_t)n*C_N + c4) = ov;
  *(u16x4*)(xr + (size_t)n*C_N + c4) = orr;
}

// ---------------------------------------------------------------------------
// Fused k/v/r GEMM: C[M x 2304] = A_z (M x 768) * Wall^T, 128x128 tiles.
// T3-minimum pipeline: double-buffered LDS, next-tile global_load_lds ISSUED
// BEFORE current-tile ds_read+MFMA, one __syncthreads (vmcnt drain) per step.
// T2 XOR-swizzle kept (pre-swizzled global source + swizzled ds_read).
// Epilogue: z=0 -> kp (f32); z=1 -> vp (f32); z=2 -> sigmoid -> srb (bf16).
// ---------------------------------------------------------------------------
__global__ __launch_bounds__(256) void gemm_kvr(
    const unsigned short* __restrict__ xk, const unsigned short* __restrict__ xv,
    const unsigned short* __restrict__ xr,
    const unsigned short* __restrict__ Wall,
    float* __restrict__ kp, float* __restrict__ vp, unsigned short* __restrict__ srb)
{
  const int m0 = blockIdx.x*128, n0 = blockIdx.y*128;
  const int z  = blockIdx.y / 6;                 // 6 n-blocks per 768 columns
  const unsigned short* A = (z==0)? xk : (z==1)? xv : xr;
  __shared__ __align__(16) unsigned short As[2][128*BK];
  __shared__ __align__(16) unsigned short Bs[2][128*BK];
  const int tid = threadIdx.x;
  const int lane = tid & 63, wid = tid >> 6;
  const int wr = wid >> 1, wc = wid & 1;
  f32x4 acc[4][4];
  #pragma unroll
  for (int i=0;i<4;++i)
    #pragma unroll
    for (int j=0;j<4;++j) acc[i][j] = (f32x4){0.f,0.f,0.f,0.f};

  const int srow = tid >> 3;                                // 0..31
  const int scol = (((tid & 7) ^ ((tid >> 3) & 7)) * 8);    // pre-swizzled src granule
  const int lr  = lane & 15;
  const int x7  = lr & 7;                                   // read-side XOR
  const int kh  = lane >> 4;                                // 0..3

  auto stage = [&](int buf, int k0){
    #pragma unroll
    for (int it=0; it<4; ++it){
      int r = it*32 + srow;
      async16(&A   [(size_t)(m0+r)*C_N + k0 + scol], &As[buf][(it*32 + wid*8)*BK]);
      async16(&Wall[(size_t)(n0+r)*C_N + k0 + scol], &Bs[buf][(it*32 + wid*8)*BK]);
    }
  };

  stage(0, 0);
  __syncthreads();
  int cur = 0;
  for (int k0 = 0; k0 < C_N; k0 += BK){
    if (k0 + BK < C_N) stage(cur^1, k0 + BK);    // prefetch next tile first
    #pragma unroll
    for (int kk=0; kk<BK; kk+=32){
      const int g = (kk>>3) + kh;                // logical granule
      const int pg = (g ^ x7) << 3;              // physical elem offset
      s16x8 af[4], bfr[4];
      #pragma unroll
      for (int mi=0;mi<4;++mi) af[mi]  = *(const s16x8*)&As[cur][(wr*64 + mi*16 + lr)*BK + pg];
      #pragma unroll
      for (int ni=0;ni<4;++ni) bfr[ni] = *(const s16x8*)&Bs[cur][(wc*64 + ni*16 + lr)*BK + pg];
      #pragma unroll
      for (int mi=0;mi<4;++mi)
        #pragma unroll
        for (int ni=0;ni<4;++ni)
          acc[mi][ni] = __builtin_amdgcn_mfma_f32_16x16x32_bf16(af[mi], bfr[ni], acc[mi][ni], 0,0,0);
    }
    __syncthreads();                              // drains prefetch + guards reuse
    cur ^= 1;
  }
  const int lr4 = (lane>>4)*4, lc = lane & 15;
  const int colbase = n0 - z*C_N;
  #pragma unroll
  for (int mi=0;mi<4;++mi){
    #pragma unroll
    for (int ni=0;ni<4;++ni){
      #pragma unroll
      for (int i=0;i<4;++i){
        int m = m0 + wr*64 + mi*16 + lr4 + i;
        int n = colbase + wc*64 + ni*16 + lc;
        float val = acc[mi][ni][i];
        if (z==0)      kp[(size_t)m*C_N + n] = val;
        else if (z==1) vp[(size_t)m*C_N + n] = val;
        else           srb[(size_t)m*C_N + n] = f2bf(1.f/(1.f + __expf(-val)));
      }
    }
  }
}

// ---------------------------------------------------------------------------
// Final GEMM: out = zp (M x C, bf16) * Wop^T — same pipelined structure.
// ---------------------------------------------------------------------------
__global__ __launch_bounds__(256) void gemm_out(
    const unsigned short* __restrict__ A, const unsigned short* __restrict__ Bw,
    float* __restrict__ out)
{
  const int m0 = blockIdx.x*128, n0 = blockIdx.y*128;
  __shared__ __align__(16) unsigned short As[2][128*BK];
  __shared__ __align__(16) unsigned short Bs[2][128*BK];
  const int tid = threadIdx.x;
  const int lane = tid & 63, wid = tid >> 6;
  const int wr = wid >> 1, wc = wid & 1;
  f32x4 acc[4][4];
  #pragma unroll
  for (int i=0;i<4;++i)
    #pragma unroll
    for (int j=0;j<4;++j) acc[i][j] = (f32x4){0.f,0.f,0.f,0.f};

  const int srow = tid >> 3;
  const int scol = (((tid & 7) ^ ((tid >> 3) & 7)) * 8);
  const int lr  = lane & 15;
  const int x7  = lr & 7;
  const int kh  = lane >> 4;

  auto stage = [&](int buf, int k0){
    #pragma unroll
    for (int it=0; it<4; ++it){
      int r = it*32 + srow;
      async16(&A [(size_t)(m0+r)*C_N + k0 + scol], &As[buf][(it*32 + wid*8)*BK]);
      async16(&Bw[(size_t)(n0+r)*C_N + k0 + scol], &Bs[buf][(it*32 + wid*8)*BK]);
    }
  };

  stage(0, 0);
  __syncthreads();
  int cur = 0;
  for (int k0 = 0; k0 < C_N; k0 += BK){
    if (k0 + BK < C_N) stage(cur^1, k0 + BK);
    #pragma unroll
    for (int kk=0; kk<BK; kk+=32){
      const int g = (kk>>3) + kh;
      const int pg = (g ^ x7) << 3;
      s16x8 af[4], bfr[4];
      #pragma unroll
      for (int mi=0;mi<4;++mi) af[mi]  = *(const s16x8*)&As[cur][(wr*64 + mi*16 + lr)*BK + pg];
      #pragma unroll
      for (int ni=0;ni<4;++ni) bfr[ni] = *(const s16x8*)&Bs[cur][(wc*64 + ni*16 + lr)*BK + pg];
      #pragma unroll
      for (int mi=0;mi<4;++mi)
        #pragma unroll
        for (int ni=0;ni<4;++ni)
          acc[mi][ni] = __builtin_amdgcn_mfma_f32_16x16x32_bf16(af[mi], bfr[ni], acc[mi][ni], 0,0,0);
    }
    __syncthreads();
    cur ^= 1;
  }
  const int lr4 = (lane>>4)*4, lc = lane & 15;
  #pragma unroll
  for (int mi=0;mi<4;++mi)
    #pragma unroll
    for (int ni=0;ni<4;++ni)
      #pragma unroll
      for (int i=0;i<4;++i){
        int m = m0 + wr*64 + mi*16 + lr4 + i;
        int n = n0 + wc*64 + ni*16 + lc;
        out[(size_t)m*C_N + n] = acc[mi][ni][i];
      }
}

// ---------------------------------------------------------------------------
// WKV chunked scan (verified round 3). srb is bf16.
// ---------------------------------------------------------------------------
__global__ __launch_bounds__(256) void wkv_phase1(
    const float* __restrict__ kp, const float* __restrict__ vp,
    const float* __restrict__ decay,
    float* __restrict__ sa, float* __restrict__ sb, float* __restrict__ sp)
{
  int g = blockIdx.x*256 + threadIdx.x;   // [0, NCH*B_N*C_N)
  int j = g % C_N;
  int cb = g / C_N;
  int b = cb % B_N, c = cb / B_N;
  float w = -__expf(decay[j] * (1.0f/T_N));
  float a = 0.f, bb = 0.f, p = -1e38f;
  size_t base = ((size_t)b*T_N + c*LCH)*C_N + j;
  #pragma unroll 4
  for (int t = 0; t < LCH; ++t){
    size_t o = base + (size_t)t*C_N;
    float kt = kp[o], vt = vp[o];
    float pw = p + w;
    float q2 = fmaxf(pw, kt);
    float e1 = __expf(pw - q2), e2 = __expf(kt - q2);
    a  = e1*a + e2*vt;
    bb = e1*bb + e2;
    p  = q2;
  }
  sa[g] = a; sb[g] = bb; sp[g] = p;
}

__global__ __launch_bounds__(256) void wkv_phase2(
    const float* __restrict__ decay,
    float* __restrict__ sa, float* __restrict__ sb, float* __restrict__ sp)
{
  int g = blockIdx.x*256 + threadIdx.x;   // [0, B_N*C_N)
  int j = g % C_N, b = g / C_N;
  float w = -__expf(decay[j] * (1.0f/T_N));
  float wL = w * (float)LCH;
  float a = 0.f, bb = 0.f, p = -1e38f;
  for (int c = 0; c < NCH; ++c){
    size_t idx = ((size_t)c*B_N + b)*C_N + j;
    float la = sa[idx], lb = sb[idx], lp = sp[idx];
    sa[idx] = a; sb[idx] = bb; sp[idx] = p;   // incoming state for chunk c
    float p1 = p + wL;
    float pn = fmaxf(p1, lp);
    float e1 = __expf(p1 - pn), e2 = __expf(lp - pn);
    a  = e1*a + e2*la;
    bb = e1*bb + e2*lb;
    p  = pn;
  }
}

__global__ __launch_bounds__(256) void wkv_phase3(
    const float* __restrict__ kp, const float* __restrict__ vp,
    const unsigned short* __restrict__ srb,
    const float* __restrict__ decay, const float* __restrict__ first,
    const float* __restrict__ sa, const float* __restrict__ sb,
    const float* __restrict__ sp,
    unsigned short* __restrict__ zp)
{
  int g = blockIdx.x*256 + threadIdx.x;   // [0, NCH*B_N*C_N)
  int j = g % C_N;
  int cb = g / C_N;
  int b = cb % B_N, c = cb / B_N;
  float w = -__expf(decay[j] * (1.0f/T_N));
  float u = first[j] * (1.0f/T_N);
  float a = sa[g], bb = sb[g], p = sp[g];
  size_t base = ((size_t)b*T_N + c*LCH)*C_N + j;
  #pragma unroll 2
  for (int t = 0; t < LCH; ++t){
    size_t o = base + (size_t)t*C_N;
    float kt = kp[o], vt = vp[o];
    float uk = u + kt;
    float q  = fmaxf(p, uk);
    float e1 = __expf(p - q), e2 = __expf(uk - q);
    float y  = __fdividef(e1*a + e2*vt, e1*bb + e2);
    zp[o] = f2bf(bf2f(srb[o]) * y);
    float pw = p + w;
    float q2 = fmaxf(pw, kt);
    float e1b = __expf(pw - q2), e2b = __expf(kt - q2);
    a  = e1b*a + e2b*vt;
    bb = e1b*bb + e2b;
    p  = q2;
  }
}

// ---------------------------------------------------------------------------
extern "C" void kernel_launch(void* const* d_in, const int* in_sizes, int n_in,
                              void* d_out, int out_size, void* d_ws, size_t ws_size,
                              hipStream_t stream)
{
  const float* x     = (const float*)d_in[0];
  const float* Wk    = (const float*)d_in[1];
  const float* Wv    = (const float*)d_in[2];
  const float* Wr    = (const float*)d_in[3];
  const float* Wo    = (const float*)d_in[4];
  const float* decay = (const float*)d_in[5];
  const float* first = (const float*)d_in[6];
  const float* mk    = (const float*)d_in[7];
  const float* mv    = (const float*)d_in[8];
  const float* mr    = (const float*)d_in[9];
  const int*   perm  = (const int*)d_in[10];
  float* out = (float*)d_out;

  char* ws = (char*)d_ws;
  size_t off = 0;
  auto alloc = [&](size_t bytes)->char* {
    char* p = ws + off;
    off += (bytes + 255) & ~(size_t)255;
    return p;
  };
  const size_t MC = (size_t)M_N * C_N;       // 6291456
  const size_t CC = (size_t)C_N * C_N;       // 589824
  const size_t SC = (size_t)NCH * B_N * C_N; // 196608
  unsigned short* xk   = (unsigned short*)alloc(MC*2);
  unsigned short* xv   = (unsigned short*)alloc(MC*2);
  unsigned short* xr   = (unsigned short*)alloc(MC*2);
  unsigned short* zp   = (unsigned short*)alloc(MC*2);
  unsigned short* Wall = (unsigned short*)alloc(CC*3*2);  // k,v,r contiguous
  unsigned short* Wop  = (unsigned short*)alloc(CC*2);
  unsigned short* srb  = (unsigned short*)alloc(MC*2);
  float* kp  = (float*)alloc(MC*4);
  float* vp  = (float*)alloc(MC*4);
  float* sa  = (float*)alloc(SC*4);
  float* sb  = (float*)alloc(SC*4);
  float* sp  = (float*)alloc(SC*4);

  prep_weights<<<dim3(CC/256), dim3(256), 0, stream>>>(Wk, Wv, Wr, Wo, perm,
                                                       Wall, Wop);
  mix_kernel<<<dim3(MC/4/256), dim3(256), 0, stream>>>(x, mk, mv, mr, xk, xv, xr);
  gemm_kvr<<<dim3(M_N/128, 3*C_N/128), dim3(256), 0, stream>>>(
      xk, xv, xr, Wall, kp, vp, srb);
  wkv_phase1<<<dim3(SC/256), dim3(256), 0, stream>>>(kp, vp, decay, sa, sb, sp);
  wkv_phase2<<<dim3(B_N*C_N/256), dim3(256), 0, stream>>>(decay, sa, sb, sp);
  wkv_phase3<<<dim3(SC/256), dim3(256), 0, stream>>>(kp, vp, srb, decay, first,
                                                     sa, sb, sp, zp);
  gemm_out<<<dim3(M_N/128, C_N/128), dim3(256), 0, stream>>>(zp, Wop, out);
}